// Round 3
// baseline (47216.983 us; speedup 1.0000x reference)
//
#include <hip/hip_runtime.h>
#include <hip/hip_bf16.h>

// Persistent-scan decoder. B=2048, T=256, H=512, P=64, PD=32, AD=128, V=12.
// One kernel runs all 256 steps; 512 blocks x 512 threads, guaranteed co-resident
// (LDS 63KB <= 80KB, VGPR capped 128 via __launch_bounds__(512,4) -> 2 blocks/CU
// capacity = 1024 slots >= 512). Grid sync = monotonic atomic barrier
// (threadfence release -> atomicAdd -> spin -> threadfence acquire; XCD-safe).
// Per step: phase A (small GEMM Uh/beta + attention with d-split + out head t-1),
// barrier, phase B (gates GEMM K=576 tile 64x128 + fused LSTM cell), barrier.

typedef __attribute__((ext_vector_type(8))) short short8;
typedef __attribute__((ext_vector_type(4))) float floatx4;

#define DEV static __device__ __forceinline__

DEV unsigned short f2bf(float f) {
    unsigned int u = __float_as_uint(f);
    unsigned int r = (u + 0x7FFFu + ((u >> 16) & 1u)) >> 16;
    return (unsigned short)r;
}
DEV float bf2f(unsigned short u) { return __uint_as_float(((unsigned int)u) << 16); }
DEV float rcp_f(float x) { float r; asm("v_rcp_f32 %0, %1" : "=v"(r) : "v"(x)); return r; }
DEV float tanh_f(float x) {
    float ax = fabsf(x);
    float e2 = __expf(2.f * ax);                 // e^{2|x|}; inf for large -> t=1
    float t = 1.f - 2.f * rcp_f(e2 + 1.f);
    return copysignf(t, x);
}
DEV float sigm(float x) { return rcp_f(1.f + __expf(-x)); }

// ---------------- workspace layout (bytes) ----------------
#define OFF_XH0    ((size_t)0)          // bf16 [2048][576] (0:512 h, 512:524 x, 524:556 ctx*beta, 556:576 zero)
#define OFF_XH1    ((size_t)2359296)
#define OFF_C      ((size_t)4718592)    // f32 [2048][512]
#define OFF_WS2    ((size_t)8912896)    // bf16 [2048][16][64][8]
#define OFF_PARTS  ((size_t)42467328)   // f32 [2048][64][32]
#define OFF_AVG    ((size_t)59244544)   // f32 [2048][64]
#define OFF_WBIG   ((size_t)59768832)   // bf16 [2048][576], row p=4j+g -> orig g*512+j
#define OFF_WSMALL ((size_t)62128128)   // bf16 [192][512]: Uw(128), betaw(32), zero(32)
#define OFF_BIAS   ((size_t)62324736)   // f32 [2048] b_ih+b_hh
#define OFF_BAR    ((size_t)62332928)   // int barrier counter
// total ~62.3 MB

DEV void gbar(int* bar, int target) {
    __syncthreads();
    if (threadIdx.x == 0) {
        __threadfence();                              // release this block's writes
        atomicAdd(bar, 1);
        while (__hip_atomic_load(bar, __ATOMIC_RELAXED, __HIP_MEMORY_SCOPE_AGENT) < target)
            __builtin_amdgcn_s_sleep(2);
        __threadfence();                              // acquire (invalidate L1/L2)
    }
    __syncthreads();
}

__global__ void k_init(int* bar) { if (threadIdx.x == 0) bar[0] = 0; }

__global__ void k_avg(const float* __restrict__ img, float* __restrict__ avg) {
    int idx = blockIdx.x * 256 + threadIdx.x;
    int b = idx >> 6, p = idx & 63;
    const float* base = img + (size_t)b * 2048 + p;
    float s = 0.f;
#pragma unroll
    for (int k = 0; k < 32; ++k) s += base[k * 64];
    avg[idx] = s * (1.f / 32.f);
}

__global__ void k_prep(const float* __restrict__ Whh, const float* __restrict__ Wih,
                       const float* __restrict__ Uw, const float* __restrict__ betaw,
                       const float* __restrict__ bih, const float* __restrict__ bhh,
                       unsigned short* __restrict__ Wbig, unsigned short* __restrict__ Wsmall,
                       float* __restrict__ bias_cat) {
    int p = blockIdx.x, tid = threadIdx.x;
    int g = p & 3, j = p >> 2, orig = g * 512 + j;
    for (int k = tid; k < 576; k += 256) {
        float v = 0.f;
        if (k < 512) v = Whh[(size_t)orig * 512 + k];
        else if (k < 556) v = Wih[(size_t)orig * 44 + (k - 512)];
        Wbig[(size_t)p * 576 + k] = f2bf(v);
    }
    if (p < 192) {
        for (int k = tid; k < 512; k += 256) {
            float v = 0.f;
            if (p < 128) v = Uw[(size_t)p * 512 + k];
            else if (p < 160) v = betaw[(size_t)(p - 128) * 512 + k];
            Wsmall[(size_t)p * 512 + k] = f2bf(v);
        }
    }
    if (tid == 0) bias_cat[orig] = bih[orig] + bhh[orig];
}

__global__ __launch_bounds__(512) void k_h0c0(const float* __restrict__ avg,
                                              const float* __restrict__ ihw, const float* __restrict__ ihb,
                                              const float* __restrict__ icw, const float* __restrict__ icb,
                                              unsigned short* __restrict__ xh0, unsigned short* __restrict__ xh1,
                                              float* __restrict__ c) {
    __shared__ float avg_s[8][64];
    int b0 = blockIdx.x * 8, tid = threadIdx.x;
    for (int i = tid; i < 8 * 64; i += 512) avg_s[i >> 6][i & 63] = avg[b0 * 64 + i];
    __syncthreads();
    int j = tid;
    float w0[64];
#pragma unroll
    for (int p4 = 0; p4 < 16; ++p4) {
        float4 v = ((const float4*)(ihw + j * 64))[p4];
        w0[p4 * 4 + 0] = v.x; w0[p4 * 4 + 1] = v.y; w0[p4 * 4 + 2] = v.z; w0[p4 * 4 + 3] = v.w;
    }
    float bh = ihb[j];
#pragma unroll
    for (int bb = 0; bb < 8; ++bb) {
        float s = bh;
#pragma unroll
        for (int p = 0; p < 64; ++p) s += w0[p] * avg_s[bb][p];
        xh0[(size_t)(b0 + bb) * 576 + j] = f2bf(tanh_f(s));
        if (j < 20) {
            xh0[(size_t)(b0 + bb) * 576 + 556 + j] = 0;
            xh1[(size_t)(b0 + bb) * 576 + 556 + j] = 0;
        }
    }
#pragma unroll
    for (int p4 = 0; p4 < 16; ++p4) {
        float4 v = ((const float4*)(icw + j * 64))[p4];
        w0[p4 * 4 + 0] = v.x; w0[p4 * 4 + 1] = v.y; w0[p4 * 4 + 2] = v.z; w0[p4 * 4 + 3] = v.w;
    }
    float bc = icb[j];
#pragma unroll
    for (int bb = 0; bb < 8; ++bb) {
        float s = bc;
#pragma unroll
        for (int p = 0; p < 64; ++p) s += w0[p] * avg_s[bb][p];
        c[(size_t)(b0 + bb) * 512 + j] = tanh_f(s);
    }
}

__global__ __launch_bounds__(256) void k_ws(const float* __restrict__ img, const float* __restrict__ Ww,
                                            const float* __restrict__ Wb, unsigned short* __restrict__ Ws2,
                                            float* __restrict__ parts) {
    __shared__ float pl[64][33];
    __shared__ float wl[32 * 128];
    int b = blockIdx.x, tid = threadIdx.x;
    const float* ib = img + (size_t)b * 2048;
    for (int i = tid; i < 2048; i += 256) pl[i & 63][i >> 6] = ib[i];
    for (int i = tid; i < 4096; i += 256) wl[(i & 31) * 128 + (i >> 5)] = Ww[i];
    __syncthreads();
    for (int i = tid; i < 2048; i += 256) parts[(size_t)b * 2048 + i] = pl[i >> 5][i & 31];
#pragma unroll
    for (int r = 0; r < 32; ++r) {
        int o = tid + r * 256;
        int p = o >> 7, d = o & 127;
        float s = Wb[d];
#pragma unroll
        for (int k = 0; k < 32; ++k) s += pl[p][k] * wl[k * 128 + d];
        Ws2[(size_t)b * 8192 + (size_t)(d >> 3) * 512 + p * 8 + (d & 7)] = f2bf(s);
    }
}

__global__ __launch_bounds__(512, 4) void k_scan(
    unsigned short* __restrict__ xh0, unsigned short* __restrict__ xh1,
    float* __restrict__ c,
    const unsigned short* __restrict__ Ws2, const float* __restrict__ parts,
    const unsigned short* __restrict__ Wsmall, const unsigned short* __restrict__ Wbig,
    const float* __restrict__ bias_cat,
    const float* __restrict__ Ub, const float* __restrict__ betab,
    const float* __restrict__ vw, const float* __restrict__ vb,
    const float* __restrict__ label, const float* __restrict__ ow, const float* __restrict__ ob,
    float* __restrict__ out_alpha, float* __restrict__ out_logits,
    int* __restrict__ bar)
{
    __shared__ float ows[12][512];    // 24 KB, persistent
    __shared__ float vws[128];
    __shared__ float uhl[4][192];
    __shared__ float sp[4][64];
    __shared__ float al[4][64];
    __shared__ float outs[4][12];
    __shared__ float gt[64][129];     // 33 KB

    const int tid = threadIdx.x, w = tid >> 6, lane = tid & 63;
    const int blk = blockIdx.x;
    const int b0 = blk * 4;                      // phase A: 4 b's per block
    const int mbase = (blk & 31) * 64;           // phase B tile
    const int nbase = (blk >> 5) * 128;
    const int jbase = (blk >> 5) * 32;
    const int jl = tid & 31;
    const float bi  = bias_cat[jbase + jl];
    const float bfv = bias_cat[512 + jbase + jl];
    const float bg  = bias_cat[1024 + jbase + jl];
    const float bo  = bias_cat[1536 + jbase + jl];

    for (int i = tid; i < 12 * 512; i += 512) ows[i >> 9][i & 511] = ow[i];
    if (tid < 128) vws[tid] = vw[tid];
    const float vb0 = vb[0];
    int barcnt = 0;

    for (int t = 0; t <= 256; ++t) {
        unsigned short* xin  = (t & 1) ? xh1 : xh0;
        unsigned short* xout = (t & 1) ? xh0 : xh1;

        // ---------- phase A ----------
        if (t < 256 && w < 4) {
            // small GEMM: uh/beta for b0..b0+3 (M=16 tile, 4 valid rows)
            int mr = b0 + (lane & 15); if (mr > 2047) mr = 2047;
            const unsigned short* Ap = xin + (size_t)mr * 576 + (lane >> 4) * 8;
            const unsigned short* Bp = Wsmall + (size_t)(48 * w + (lane & 15)) * 512 + (lane >> 4) * 8;
            floatx4 a0 = {}, a1 = {}, a2 = {};
#pragma unroll 4
            for (int k0 = 0; k0 < 512; k0 += 32) {
                short8 a = *(const short8*)(Ap + k0);
                short8 q0 = *(const short8*)(Bp + k0);
                short8 q1 = *(const short8*)(Bp + 16 * 512 + k0);
                short8 q2 = *(const short8*)(Bp + 32 * 512 + k0);
                a0 = __builtin_amdgcn_mfma_f32_16x16x32_bf16(a, q0, a0, 0, 0, 0);
                a1 = __builtin_amdgcn_mfma_f32_16x16x32_bf16(a, q1, a1, 0, 0, 0);
                a2 = __builtin_amdgcn_mfma_f32_16x16x32_bf16(a, q2, a2, 0, 0, 0);
            }
            int cc = lane & 15, r0q = (lane >> 4) * 4;
#pragma unroll
            for (int jt = 0; jt < 3; ++jt) {
                floatx4 av = (jt == 0) ? a0 : (jt == 1) ? a1 : a2;
#pragma unroll
                for (int r = 0; r < 4; ++r) {
                    int m = r0q + r, n = 48 * w + jt * 16 + cc;
                    if (m < 4 && n < 160) uhl[m][n] = av[r] + (n < 128 ? Ub[n] : betab[n - 128]);
                }
            }
        }
        if (t > 0 && w >= 4) {
            // output head for step t-1, b = b0 + (w-4)
            int b = b0 + (w - 4);
            const unsigned short* hp = xin + (size_t)b * 576;
            float hreg[8];
#pragma unroll
            for (int q = 0; q < 8; ++q) hreg[q] = bf2f(hp[lane + 64 * q]);
#pragma unroll
            for (int v = 0; v < 12; ++v) {
                float p = 0.f;
#pragma unroll
                for (int q = 0; q < 8; ++q) p += hreg[q] * ows[v][lane + 64 * q];
#pragma unroll
                for (int o = 32; o; o >>= 1) p += __shfl_xor(p, o);
                if (lane == 0) outs[w - 4][v] = p + ob[v];
            }
            float x = (lane < 12) ? outs[w - 4][lane] : -1e30f;
            float lse = 0.f;
            if (lane == 0) {
                float mx = outs[w - 4][0];
#pragma unroll
                for (int v = 1; v < 12; ++v) mx = fmaxf(mx, outs[w - 4][v]);
                float ssum = 0.f;
#pragma unroll
                for (int v = 0; v < 12; ++v) ssum += __expf(outs[w - 4][v] - mx);
                lse = mx + __logf(ssum);
            }
            lse = __shfl(lse, 0);
            if (lane < 12) out_logits[((size_t)b * 256 + (t - 1)) * 12 + lane] = x - lse;
        }
        if (t == 256) break;   // final head done; uniform exit
        __syncthreads();

        {   // attention score, d-dim split across wave pairs (w, w+4)
            int bb = w & 3, b = b0 + bb, half = w >> 2;
            const unsigned short* wsp = Ws2 + (size_t)b * 8192 + (size_t)(half * 8) * 512 + lane * 8;
            float s = half ? 0.f : vb0;
#pragma unroll
            for (int dg2 = 0; dg2 < 8; ++dg2) {
                short8 wv = *(const short8*)(wsp + (size_t)dg2 * 512);
#pragma unroll
                for (int dd = 0; dd < 8; ++dd) {
                    int d = (half * 8 + dg2) * 8 + dd;
                    s += vws[d] * tanh_f(bf2f((unsigned short)wv[dd]) + uhl[bb][d]);
                }
            }
            if (half) sp[bb][lane] = s;
            __syncthreads();
            if (!half) {
                s += sp[bb][lane];
                float m = s;
#pragma unroll
                for (int o = 32; o; o >>= 1) m = fmaxf(m, __shfl_xor(m, o));
                float e = __expf(s - m);
                float sum = e;
#pragma unroll
                for (int o = 32; o; o >>= 1) sum += __shfl_xor(sum, o);
                float alpha = e * rcp_f(sum);
                out_alpha[((size_t)t * 2048 + b) * 64 + lane] = alpha;
                al[bb][lane] = alpha;
                int k = lane & 31, hh = lane >> 5;
                const float* pb = parts + (size_t)b * 2048;
                float cp = 0.f;
#pragma unroll
                for (int p = 0; p < 32; ++p) {
                    int pp = hh * 32 + p;
                    cp += al[bb][pp] * pb[pp * 32 + k];
                }
                cp += __shfl_xor(cp, 32);
                if (hh == 0)
                    xin[(size_t)b * 576 + 524 + k] = f2bf(cp * sigm(uhl[bb][128 + k]));
                if (lane < 12)
                    xin[(size_t)b * 576 + 512 + lane] = f2bf(label[((size_t)b * 256 + t) * 12 + lane]);
            }
        }

        gbar(bar, 512 * (++barcnt));

        // ---------- phase B: gates GEMM + cell ----------
        {
            const unsigned short* Ap = xin + (size_t)(mbase + (w >> 2) * 32 + (lane & 15)) * 576 + (lane >> 4) * 8;
            const unsigned short* Bp = Wbig + (size_t)(nbase + (w & 3) * 32 + (lane & 15)) * 576 + (lane >> 4) * 8;
            floatx4 acc00 = {}, acc01 = {}, acc10 = {}, acc11 = {};
#pragma unroll 3
            for (int k0 = 0; k0 < 576; k0 += 32) {
                short8 av0 = *(const short8*)(Ap + k0);
                short8 av1 = *(const short8*)(Ap + 16 * 576 + k0);
                short8 bv0 = *(const short8*)(Bp + k0);
                short8 bv1 = *(const short8*)(Bp + 16 * 576 + k0);
                acc00 = __builtin_amdgcn_mfma_f32_16x16x32_bf16(av0, bv0, acc00, 0, 0, 0);
                acc01 = __builtin_amdgcn_mfma_f32_16x16x32_bf16(av0, bv1, acc01, 0, 0, 0);
                acc10 = __builtin_amdgcn_mfma_f32_16x16x32_bf16(av1, bv0, acc10, 0, 0, 0);
                acc11 = __builtin_amdgcn_mfma_f32_16x16x32_bf16(av1, bv1, acc11, 0, 0, 0);
            }
            int cc = lane & 15, r0q = (lane >> 4) * 4;
#pragma unroll
            for (int i = 0; i < 2; ++i)
#pragma unroll
                for (int jt = 0; jt < 2; ++jt) {
                    floatx4 av = (i == 0) ? (jt == 0 ? acc00 : acc01) : (jt == 0 ? acc10 : acc11);
                    int pl = (w & 3) * 32 + jt * 16 + cc;
                    int colb = (pl & 3) * 32 + (pl >> 2);
                    int mlb = (w >> 2) * 32 + i * 16 + r0q;
#pragma unroll
                    for (int r = 0; r < 4; ++r) gt[mlb + r][colb] = av[r];
                }
            __syncthreads();
#pragma unroll
            for (int it = 0; it < 4; ++it) {
                int bl = (tid >> 5) * 4 + it;
                int b = mbase + bl;
                float gi = gt[bl][jl] + bi;
                float gf = gt[bl][32 + jl] + bfv;
                float gg = gt[bl][64 + jl] + bg;
                float go = gt[bl][96 + jl] + bo;
                size_t hc = (size_t)b * 512 + jbase + jl;
                float cold = c[hc];
                float c2 = sigm(gf) * cold + sigm(gi) * tanh_f(gg);
                float h2 = sigm(go) * tanh_f(c2);
                c[hc] = c2;
                xout[(size_t)b * 576 + jbase + jl] = f2bf(h2);
            }
        }

        gbar(bar, 512 * (++barcnt));
    }
}

extern "C" void kernel_launch(void* const* d_in, const int* in_sizes, int n_in,
                              void* d_out, int out_size, void* d_ws, size_t ws_size,
                              hipStream_t stream) {
    const float* img   = (const float*)d_in[0];
    const float* label = (const float*)d_in[1];
    const float* Ww    = (const float*)d_in[2];
    const float* Wb    = (const float*)d_in[3];
    const float* Uw    = (const float*)d_in[4];
    const float* Ub    = (const float*)d_in[5];
    const float* vw    = (const float*)d_in[6];
    const float* vb    = (const float*)d_in[7];
    const float* betaw = (const float*)d_in[8];
    const float* betab = (const float*)d_in[9];
    const float* ihw   = (const float*)d_in[10];
    const float* ihb   = (const float*)d_in[11];
    const float* icw   = (const float*)d_in[12];
    const float* icb   = (const float*)d_in[13];
    const float* Wih   = (const float*)d_in[14];
    const float* Whh   = (const float*)d_in[15];
    const float* bih   = (const float*)d_in[16];
    const float* bhh   = (const float*)d_in[17];
    const float* ow    = (const float*)d_in[18];
    const float* ob    = (const float*)d_in[19];

    char* ws = (char*)d_ws;
    unsigned short* xh0    = (unsigned short*)(ws + OFF_XH0);
    unsigned short* xh1    = (unsigned short*)(ws + OFF_XH1);
    float*          c      = (float*)(ws + OFF_C);
    unsigned short* Ws2    = (unsigned short*)(ws + OFF_WS2);
    float*          parts  = (float*)(ws + OFF_PARTS);
    float*          avg    = (float*)(ws + OFF_AVG);
    unsigned short* Wbig   = (unsigned short*)(ws + OFF_WBIG);
    unsigned short* Wsmall = (unsigned short*)(ws + OFF_WSMALL);
    float*          bias   = (float*)(ws + OFF_BIAS);
    int*            bar    = (int*)(ws + OFF_BAR);

    float* out_logits = (float*)d_out;
    float* out_alpha  = out_logits + (size_t)2048 * 256 * 12;

    k_init<<<1, 64, 0, stream>>>(bar);
    k_avg<<<512, 256, 0, stream>>>(img, avg);
    k_prep<<<2048, 256, 0, stream>>>(Whh, Wih, Uw, betaw, bih, bhh, Wbig, Wsmall, bias);
    k_h0c0<<<256, 512, 0, stream>>>(avg, ihw, ihb, icw, icb, xh0, xh1, c);
    k_ws<<<2048, 256, 0, stream>>>(img, Ww, Wb, Ws2, parts);

    k_scan<<<512, 512, 0, stream>>>(xh0, xh1, c, Ws2, parts, Wsmall, Wbig, bias,
                                    Ub, betab, vw, vb, label, ow, ob,
                                    out_alpha, out_logits, bar);
}